// Round 2
// baseline (462.144 us; speedup 1.0000x reference)
//
#include <hip/hip_runtime.h>
#include <hip/hip_bf16.h>

// Problem constants (match reference)
constexpr int Bn = 16384;
constexpr int S  = 64;
constexpr int H  = 256;
constexpr int E  = 8;

// One block per row b, 256 threads (= H). Fused:
//   pooled = mean_s x[b,s,:]        (1 GB HBM read -> the roofline term)
//   logits = xr[b] @ W_router       (f64 accum to avoid top-2 tie flips)
//   top-2 + softmax(2)
//   out[b,d] = w0*tanh(pooled.W[e0,:,d]) + w1*tanh(pooled.W[e1,:,d])  (f32!)
__global__ __launch_bounds__(256) void moe_fused_kernel(
    const float* __restrict__ x,
    const float* __restrict__ xr,
    const float* __restrict__ Wr,      // [H][E]
    const float* __restrict__ We,      // [E][H][H]
    const float* __restrict__ be,      // [E][H]
    float* __restrict__ out)           // [B][H] float32
{
    const int b = blockIdx.x;
    const int t = threadIdx.x;

    __shared__ float  pooled[H];
    __shared__ float  xr_s[H];
    __shared__ float4 red4[4][64];
    __shared__ float  logits_s[E];
    __shared__ int    sel[2];
    __shared__ float  wsel[2];

    // ---- Phase 1: mean-pool over S with float4 coalesced loads ----
    {
        const float4* xrow = reinterpret_cast<const float4*>(x + (size_t)b * S * H);
        const int c4 = t & 63;   // float4 column within the H=256 row (64 float4)
        const int sg = t >> 6;   // s-group 0..3
        float4 acc = make_float4(0.f, 0.f, 0.f, 0.f);
#pragma unroll
        for (int i = 0; i < 16; ++i) {
            const int s = sg + 4 * i;
            float4 v = xrow[s * 64 + c4];
            acc.x += v.x; acc.y += v.y; acc.z += v.z; acc.w += v.w;
        }
        red4[sg][c4] = acc;
        xr_s[t] = xr[(size_t)b * H + t];
    }
    __syncthreads();

    {
        const float* r0 = reinterpret_cast<const float*>(&red4[0][0]);
        const float* r1 = reinterpret_cast<const float*>(&red4[1][0]);
        const float* r2 = reinterpret_cast<const float*>(&red4[2][0]);
        const float* r3 = reinterpret_cast<const float*>(&red4[3][0]);
        pooled[t] = (r0[t] + r1[t] + r2[t] + r3[t]) * (1.0f / (float)S);
    }

    // ---- Phase 2: routing logits (threads 0..7), f64 accumulation ----
    if (t < E) {
        double acc = 0.0;
#pragma unroll 8
        for (int h = 0; h < H; ++h)
            acc += (double)xr_s[h] * (double)Wr[h * E + t];
        logits_s[t] = (float)acc;
    }
    __syncthreads();

    if (t == 0) {
        // top-1 (strict > keeps lowest index on ties, matching lax.top_k)
        int i0 = 0; float v0 = logits_s[0];
#pragma unroll
        for (int e = 1; e < E; ++e)
            if (logits_s[e] > v0) { v0 = logits_s[e]; i0 = e; }
        // top-2
        int i1 = -1; float v1 = -3.0e38f;
#pragma unroll
        for (int e = 0; e < E; ++e) {
            if (e == i0) continue;
            if (logits_s[e] > v1) { v1 = logits_s[e]; i1 = e; }
        }
        // softmax over the two selected logits (v0 >= v1)
        const float ex = expf(v1 - v0);
        const float inv = 1.0f / (1.0f + ex);
        sel[0] = i0; sel[1] = i1;
        wsel[0] = inv; wsel[1] = ex * inv;
    }
    __syncthreads();

    // ---- Phase 3: two expert matvecs, tanh, weighted combine ----
    {
        const int   e0 = sel[0], e1 = sel[1];
        const float w0 = wsel[0], w1 = wsel[1];
        const float* __restrict__ W0 = We + (size_t)e0 * H * H + t;
        const float* __restrict__ W1 = We + (size_t)e1 * H * H + t;
        float a0 = be[e0 * H + t];
        float a1 = be[e1 * H + t];
#pragma unroll 8
        for (int h = 0; h < H; ++h) {
            const float p = pooled[h];           // LDS broadcast (conflict-free)
            a0 = fmaf(p, W0[(size_t)h * H], a0); // lane-coalesced, L2-resident
            a1 = fmaf(p, W1[(size_t)h * H], a1);
        }
        const float r = w0 * tanhf(a0) + w1 * tanhf(a1);
        out[(size_t)b * H + t] = r;
    }
}

extern "C" void kernel_launch(void* const* d_in, const int* in_sizes, int n_in,
                              void* d_out, int out_size, void* d_ws, size_t ws_size,
                              hipStream_t stream) {
    const float* x  = (const float*)d_in[0];   // [B,S,H]
    const float* xr = (const float*)d_in[1];   // [B,H]
    const float* Wr = (const float*)d_in[2];   // [H,E]
    const float* We = (const float*)d_in[3];   // [E,H,H]
    const float* be = (const float*)d_in[4];   // [E,H]
    float* out = (float*)d_out;

    (void)in_sizes; (void)n_in; (void)out_size; (void)d_ws; (void)ws_size;

    moe_fused_kernel<<<Bn, H, 0, stream>>>(x, xr, Wr, We, be, out);
}

// Round 3
// 308.587 us; speedup vs baseline: 1.4976x; 1.4976x over previous
//
#include <hip/hip_runtime.h>
#include <hip/hip_bf16.h>

// Problem constants (match reference)
constexpr int Bn = 16384;
constexpr int S  = 64;
constexpr int H  = 256;
constexpr int E  = 8;

constexpr int RPB  = 32;           // rows per block (main kernel)
constexpr int NBLK = Bn / RPB;     // 512 blocks
constexpr int TPB  = 512;          // 8 waves
constexpr int PSTR = H + 8;        // 264 bf16 -> 528 B row stride (16B-aligned, 2-way banks = free)

typedef short bf16x8 __attribute__((ext_vector_type(8)));
typedef float f32x4  __attribute__((ext_vector_type(4)));

__device__ __forceinline__ float fast_tanh(float x) {
    const float ex = __expf(2.0f * x);
    return (ex - 1.0f) / (ex + 1.0f);
}

// ---------------------------------------------------------------------------
// Prep: Wt[e][d][h] (bf16) = We[e][h][d] (f32).  k(=h)-contiguous for MFMA B-frags.
// Grid: 32 blocks = 8 experts x 4 h-chunks of 64. 256 threads.
// ---------------------------------------------------------------------------
__global__ __launch_bounds__(256) void prep_wt(const float* __restrict__ We,
                                               __hip_bfloat16* __restrict__ Wt) {
    __shared__ __hip_bfloat16 tile[64][H + 4];   // stride 260 bf16 = 520 B
    const int e    = blockIdx.x >> 2;
    const int hblk = blockIdx.x & 3;
    const int t    = threadIdx.x;

    const float* src = We + ((size_t)e * H + hblk * 64) * H;   // 64 h-rows x 256 d
#pragma unroll
    for (int i = 0; i < 16; ++i) {
        const int idx = t + 256 * i;    // 0..4095
        const int hh  = idx >> 6;       // 0..63
        const int c4  = idx & 63;
        float4 v = reinterpret_cast<const float4*>(src + (size_t)hh * H)[c4];
        tile[hh][c4 * 4 + 0] = __float2bfloat16(v.x);
        tile[hh][c4 * 4 + 1] = __float2bfloat16(v.y);
        tile[hh][c4 * 4 + 2] = __float2bfloat16(v.z);
        tile[hh][c4 * 4 + 3] = __float2bfloat16(v.w);
    }
    __syncthreads();

    const int h  = t & 63;     // coalesced in h on the write side
    const int dd = t >> 6;     // 0..3
#pragma unroll
    for (int j = 0; j < 64; ++j) {
        const int d = j * 4 + dd;
        Wt[((size_t)e * H + d) * H + hblk * 64 + h] = tile[h][d];
    }
}

// ---------------------------------------------------------------------------
// Main fused kernel: 32 rows/block, 8 waves.
//   phase 1: mean-pool (HBM roofline term) -> bf16 LDS
//   phase 2: f64 routing logits + top-2 + softmax -> dense gate in LDS
//   phase 3: dense 8-expert MFMA GEMM (A=pooled, B=Wt), tanh, gate-combine
// Wave w: row-group rg=w>>2 (16 rows), d-group dg=w&3 (64 cols) -> 4 C-tiles.
// ---------------------------------------------------------------------------
__global__ __launch_bounds__(TPB, 4) void moe_main(
    const float* __restrict__ x,
    const float* __restrict__ xr,
    const float* __restrict__ Wr,              // [H][E]
    const float* __restrict__ be,              // [E][H]
    const __hip_bfloat16* __restrict__ Wt,     // [E][H d][H h] bf16
    float* __restrict__ out)                   // [B][H] f32
{
    const int b0 = blockIdx.x * RPB;
    const int t  = threadIdx.x;

    __shared__ __hip_bfloat16 pooled[RPB][PSTR];
    __shared__ float logit_s[RPB][E];
    __shared__ float gate_s[RPB][E];

    // ---- Phase 1: mean-pool over S, float4 coalesced ----
    {
        const int c4 = t & 63;       // float4 column (64 per row)
        const int rr = t >> 6;       // wave id 0..7
#pragma unroll
        for (int i = 0; i < RPB / 8; ++i) {
            const int r = rr + 8 * i;
            const float4* xrow = reinterpret_cast<const float4*>(x + (size_t)(b0 + r) * (S * H));
            float4 acc = make_float4(0.f, 0.f, 0.f, 0.f);
#pragma unroll 8
            for (int s = 0; s < S; ++s) {
                float4 v = xrow[(size_t)s * 64 + c4];
                acc.x += v.x; acc.y += v.y; acc.z += v.z; acc.w += v.w;
            }
            const float sc = 1.0f / (float)S;
            pooled[r][c4 * 4 + 0] = __float2bfloat16(acc.x * sc);
            pooled[r][c4 * 4 + 1] = __float2bfloat16(acc.y * sc);
            pooled[r][c4 * 4 + 2] = __float2bfloat16(acc.z * sc);
            pooled[r][c4 * 4 + 3] = __float2bfloat16(acc.w * sc);
        }
    }

    // ---- Phase 2: routing logits, f64 accumulation (one dot per thread) ----
    if (t < RPB * E) {
        const int r = t >> 3, e = t & 7;
        const float* xrp = xr + (size_t)(b0 + r) * H;
        double acc = 0.0;
#pragma unroll 8
        for (int h = 0; h < H; ++h)
            acc += (double)xrp[h] * (double)Wr[h * E + e];
        logit_s[r][e] = (float)acc;
    }
    __syncthreads();

    // ---- Phase 2b: top-2 + softmax -> dense gate ----
    if (t < RPB) {
        int i0 = 0; float v0 = logit_s[t][0];
#pragma unroll
        for (int e = 1; e < E; ++e)
            if (logit_s[t][e] > v0) { v0 = logit_s[t][e]; i0 = e; }
        int i1 = -1; float v1 = -3.0e38f;
#pragma unroll
        for (int e = 0; e < E; ++e) {
            if (e == i0) continue;
            if (logit_s[t][e] > v1) { v1 = logit_s[t][e]; i1 = e; }
        }
        const float ex  = expf(v1 - v0);
        const float inv = 1.0f / (1.0f + ex);
#pragma unroll
        for (int e = 0; e < E; ++e) gate_s[t][e] = 0.f;
        gate_s[t][i0] = inv;
        gate_s[t][i1] = ex * inv;
    }
    __syncthreads();

    // ---- Phase 3: dense 8-expert MFMA + tanh + gate combine ----
    {
        const int w  = t >> 6;
        const int l  = t & 63;
        const int rg = w >> 2;          // row-group: rows rg*16 .. +15
        const int dg = w & 3;           // d-group:  cols dg*64 .. +63
        const int lr = l & 15;
        const int lq = l >> 4;          // quarter 0..3

        f32x4 oacc[4];
#pragma unroll
        for (int n = 0; n < 4; ++n) oacc[n] = 0.f;

        const __hip_bfloat16* abase = &pooled[rg * 16 + lr][lq * 8];

        for (int e = 0; e < E; ++e) {
            f32x4 acc[4];
#pragma unroll
            for (int n = 0; n < 4; ++n) acc[n] = 0.f;

            // B base: Wt[e][d = dg*64 + n*16 + lr][h = lq*8 + kk*32 + j]
            const __hip_bfloat16* wb =
                Wt + ((size_t)e * H + dg * 64 + lr) * H + lq * 8;

#pragma unroll
            for (int kk = 0; kk < 8; ++kk) {
                const bf16x8 a = *reinterpret_cast<const bf16x8*>(abase + kk * 32);
                bf16x8 bfr[4];
#pragma unroll
                for (int n = 0; n < 4; ++n)
                    bfr[n] = *reinterpret_cast<const bf16x8*>(wb + (size_t)n * 16 * H + kk * 32);
#pragma unroll
                for (int n = 0; n < 4; ++n)
                    acc[n] = __builtin_amdgcn_mfma_f32_16x16x32_bf16(a, bfr[n], acc[n], 0, 0, 0);
            }

            // combine: out += gate[r][e] * tanh(acc + bias)
            float g[4];
#pragma unroll
            for (int j = 0; j < 4; ++j) g[j] = gate_s[rg * 16 + lq * 4 + j][e];
#pragma unroll
            for (int n = 0; n < 4; ++n) {
                const int d = dg * 64 + n * 16 + lr;
                const float bias = be[e * H + d];
#pragma unroll
                for (int j = 0; j < 4; ++j)
                    oacc[n][j] += g[j] * fast_tanh(acc[n][j] + bias);
            }
        }

        // write out (C/D layout: col = lane&15, row = (lane>>4)*4 + j)
#pragma unroll
        for (int n = 0; n < 4; ++n) {
            const int d = dg * 64 + n * 16 + lr;
#pragma unroll
            for (int j = 0; j < 4; ++j) {
                const int r = rg * 16 + lq * 4 + j;
                out[(size_t)(b0 + r) * H + d] = oacc[n][j];
            }
        }
    }
}

// ---------------------------------------------------------------------------
// Fallback (round-2 kernel, correct at 462 us) if ws is too small for Wt.
// ---------------------------------------------------------------------------
__global__ __launch_bounds__(256) void moe_fused_fallback(
    const float* __restrict__ x, const float* __restrict__ xr,
    const float* __restrict__ Wr, const float* __restrict__ We,
    const float* __restrict__ be, float* __restrict__ out)
{
    const int b = blockIdx.x;
    const int t = threadIdx.x;

    __shared__ float  pooled[H];
    __shared__ float  xr_s[H];
    __shared__ float4 red4[4][64];
    __shared__ float  logits_s[E];
    __shared__ int    sel[2];
    __shared__ float  wsel[2];

    {
        const float4* xrow = reinterpret_cast<const float4*>(x + (size_t)b * S * H);
        const int c4 = t & 63;
        const int sg = t >> 6;
        float4 acc = make_float4(0.f, 0.f, 0.f, 0.f);
#pragma unroll
        for (int i = 0; i < 16; ++i) {
            float4 v = xrow[(sg + 4 * i) * 64 + c4];
            acc.x += v.x; acc.y += v.y; acc.z += v.z; acc.w += v.w;
        }
        red4[sg][c4] = acc;
        xr_s[t] = xr[(size_t)b * H + t];
    }
    __syncthreads();
    {
        const float* r0 = reinterpret_cast<const float*>(&red4[0][0]);
        const float* r1 = reinterpret_cast<const float*>(&red4[1][0]);
        const float* r2 = reinterpret_cast<const float*>(&red4[2][0]);
        const float* r3 = reinterpret_cast<const float*>(&red4[3][0]);
        pooled[t] = (r0[t] + r1[t] + r2[t] + r3[t]) * (1.0f / (float)S);
    }
    if (t < E) {
        double acc = 0.0;
        for (int h = 0; h < H; ++h)
            acc += (double)xr_s[h] * (double)Wr[h * E + t];
        logits_s[t] = (float)acc;
    }
    __syncthreads();
    if (t == 0) {
        int i0 = 0; float v0 = logits_s[0];
        for (int e = 1; e < E; ++e)
            if (logits_s[e] > v0) { v0 = logits_s[e]; i0 = e; }
        int i1 = -1; float v1 = -3.0e38f;
        for (int e = 0; e < E; ++e) {
            if (e == i0) continue;
            if (logits_s[e] > v1) { v1 = logits_s[e]; i1 = e; }
        }
        const float ex = expf(v1 - v0);
        const float inv = 1.0f / (1.0f + ex);
        sel[0] = i0; sel[1] = i1;
        wsel[0] = inv; wsel[1] = ex * inv;
    }
    __syncthreads();
    {
        const int   e0 = sel[0], e1 = sel[1];
        const float w0 = wsel[0], w1 = wsel[1];
        const float* W0 = We + (size_t)e0 * H * H + t;
        const float* W1 = We + (size_t)e1 * H * H + t;
        float a0 = be[e0 * H + t];
        float a1 = be[e1 * H + t];
#pragma unroll 8
        for (int h = 0; h < H; ++h) {
            const float p = pooled[h];
            a0 = fmaf(p, W0[(size_t)h * H], a0);
            a1 = fmaf(p, W1[(size_t)h * H], a1);
        }
        out[(size_t)b * H + t] = w0 * tanhf(a0) + w1 * tanhf(a1);
    }
}

extern "C" void kernel_launch(void* const* d_in, const int* in_sizes, int n_in,
                              void* d_out, int out_size, void* d_ws, size_t ws_size,
                              hipStream_t stream) {
    const float* x  = (const float*)d_in[0];   // [B,S,H]
    const float* xr = (const float*)d_in[1];   // [B,H]
    const float* Wr = (const float*)d_in[2];   // [H,E]
    const float* We = (const float*)d_in[3];   // [E,H,H]
    const float* be = (const float*)d_in[4];   // [E,H]
    float* out = (float*)d_out;

    (void)in_sizes; (void)n_in; (void)out_size;

    const size_t wt_bytes = (size_t)E * H * H * sizeof(__hip_bfloat16);  // 1 MiB
    if (ws_size >= wt_bytes) {
        __hip_bfloat16* Wt = (__hip_bfloat16*)d_ws;
        prep_wt<<<32, 256, 0, stream>>>(We, Wt);
        moe_main<<<NBLK, TPB, 0, stream>>>(x, xr, Wr, be, Wt, out);
    } else {
        moe_fused_fallback<<<Bn, 256, 0, stream>>>(x, xr, Wr, We, be, out);
    }
}